// Round 9
// baseline (28781.821 us; speedup 1.0000x reference)
//
#include <hip/hip_runtime.h>

typedef __attribute__((ext_vector_type(8))) short bf16x8;
typedef __attribute__((ext_vector_type(4))) float f32x4;

__device__ __forceinline__ unsigned short f2bf(float x){
  union { float f; unsigned u; } v; v.f = x;
  unsigned r = v.u + 0x7FFFu + ((v.u >> 16) & 1u);
  return (unsigned short)(r >> 16);
}

#define BYPASS_LD(dst, base, OFF) \
  asm volatile("global_load_dwordx4 %0, %1, off offset:" #OFF " sc0" \
               : "=v"(dst) : "v"(base))
#define LD16(S, B) do{ \
  BYPASS_LD(S[0],B,0);    BYPASS_LD(S[1],B,64);   BYPASS_LD(S[2],B,128);  BYPASS_LD(S[3],B,192); \
  BYPASS_LD(S[4],B,256);  BYPASS_LD(S[5],B,320);  BYPASS_LD(S[6],B,384);  BYPASS_LD(S[7],B,448); \
  BYPASS_LD(S[8],B,512);  BYPASS_LD(S[9],B,576);  BYPASS_LD(S[10],B,640); BYPASS_LD(S[11],B,704); \
  BYPASS_LD(S[12],B,768); BYPASS_LD(S[13],B,832); BYPASS_LD(S[14],B,896); BYPASS_LD(S[15],B,960); \
}while(0)
#define WAIT_VM0() do{ asm volatile("s_waitcnt vmcnt(0)" ::: "memory"); \
                       __builtin_amdgcn_sched_barrier(0); }while(0)
#define BYPASS_ST_SHORT(base, val) \
  asm volatile("global_store_short %0, %1, off sc0 sc1" :: "v"(base), "v"(val))
#define KEEP16(S) asm volatile("" :: "v"(S[0]),"v"(S[1]),"v"(S[2]),"v"(S[3]),"v"(S[4]),\
  "v"(S[5]),"v"(S[6]),"v"(S[7]),"v"(S[8]),"v"(S[9]),"v"(S[10]),"v"(S[11]),"v"(S[12]),\
  "v"(S[13]),"v"(S[14]),"v"(S[15]))
#define KEEP8(S) asm volatile("" :: "v"(S[0]),"v"(S[1]),"v"(S[2]),"v"(S[3]),"v"(S[4]),\
  "v"(S[5]),"v"(S[6]),"v"(S[7]))

__device__ __forceinline__ int ld_flag(const int* p){
  int v;
  asm volatile("global_load_dword %0, %1, off sc0 sc1\n\t"
               "s_waitcnt vmcnt(0)"
               : "=v"(v) : "v"(p) : "memory");
  return v;
}

__device__ __forceinline__ void gload_lds16(const void* g, void* l){
  __builtin_amdgcn_global_load_lds(
      (const __attribute__((address_space(1))) unsigned*)g,
      (__attribute__((address_space(3))) unsigned*)l, 16, 0, 0);
}

// ---------------- embed + mask + flag reset ----------------
__global__ void embed_kernel(const int* __restrict__ seqs, const float* __restrict__ emb,
                             unsigned short* __restrict__ x, int* __restrict__ mask,
                             int* __restrict__ flags){
  const int t = blockIdx.x, b = blockIdx.y, l = threadIdx.x;
  if (t == 0 && b == 0){
    #pragma unroll
    for (int j = 0; j < 32; ++j) flags[l + j*64] = 0;
  }
  const int tok = seqs[b*130 + t];
  if (l == 0) mask[b*130 + t] = (tok != 0) ? 1 : 0;
  const float* src = emb + (size_t)tok * 256;
  unsigned short* dst = x + ((size_t)b*130 + t)*256;
  #pragma unroll
  for (int j = 0; j < 4; ++j) dst[l + j*64] = f2bf(src[l + j*64]);
}

// ---------------- fp32 [R,C] -> bf16 [C,R] transpose ----------------
__global__ void transpose_bf16(const float* __restrict__ in, unsigned short* __restrict__ out,
                               int R, int C){
  __shared__ float tile[32][33];
  const int c0 = blockIdx.x*32, r0 = blockIdx.y*32;
  const int tx = threadIdx.x, ty = threadIdx.y;
  #pragma unroll
  for (int j = 0; j < 32; j += 8) tile[ty+j][tx] = in[(size_t)(r0+ty+j)*C + (c0+tx)];
  __syncthreads();
  #pragma unroll
  for (int j = 0; j < 32; j += 8) out[(size_t)(c0+ty+j)*R + (r0+tx)] = f2bf(tile[tx][ty+j]);
}

// ---------------- templated LSTM ----------------
// MODE 1 = full compute (L0: h-loads issued before x-MFMAs). MODE 2 = loads
// stripped (register garbage, asm-opaqued). MODE 3 = MFMA+activation stripped.
// LDS tag (modetag) makes each instantiation identifiable in rocprof.
template<int SYNC, int MODE>
__global__ __launch_bounds__(512, 2) void lstm_kern(
    const unsigned short* __restrict__ x, const int* __restrict__ maskg,
    const unsigned short* __restrict__ fk0T, const unsigned short* __restrict__ fr0T,
    const unsigned short* __restrict__ fk1T, const unsigned short* __restrict__ fr1T,
    const unsigned short* __restrict__ bk0T, const unsigned short* __restrict__ br0T,
    const unsigned short* __restrict__ bk1T, const unsigned short* __restrict__ br1T,
    const float* __restrict__ fb0, const float* __restrict__ fb1,
    const float* __restrict__ bb0, const float* __restrict__ bb1,
    unsigned short* h0f, unsigned short* h0b,
    unsigned short* aproj, int* flags, int nsteps)
{
  const int wg = blockIdx.x;
  const int dir = wg >> 5;
  const int layer = (wg >> 4) & 1;
  const int u0 = (wg & 15) * 32;
  const int tid = threadIdx.x;
  const int w = tid >> 6, l = tid & 63;
  const int gate = w >> 1, half = w & 1;
  const int lr = l & 15, lk = l >> 4;
  const int cglob = gate*512 + u0 + half*16 + lr;

  const unsigned short* kT = (layer == 0) ? (dir ? bk0T : fk0T) : (dir ? bk1T : fk1T);
  const unsigned short* rT = (layer == 0) ? (dir ? br0T : fr0T) : (dir ? br1T : fr1T);
  const float* bias = (layer == 0) ? (dir ? bb0 : fb0) : (dir ? bb1 : fb1);
  unsigned short* h0 = dir ? h0b : h0f;

  int* fown  = flags + (layer*2 + dir)*256;
  int* fprod = flags + dir*256;
  int* fself = fown + (wg & 15)*16;

  __shared__ char modetag[MODE*512 + (SYNC ? 1 : 257)];
  if (tid == 9999) ((volatile char*)modetag)[0] = 1;

  bf16x8 wreg[16], kreg[16];
  if constexpr (MODE != 3){
    #pragma unroll
    for (int i = 0; i < 16; ++i)
      wreg[i] = *(const bf16x8*)(rT + (size_t)cglob*512 + i*32 + lk*8);
    if (layer == 0){
      #pragma unroll
      for (int i = 0; i < 8; ++i)
        kreg[i] = *(const bf16x8*)(kT + (size_t)cglob*256 + i*32 + lk*8);
    } else {
      #pragma unroll
      for (int i = 0; i < 16; ++i)
        kreg[i] = *(const bf16x8*)(kT + (size_t)cglob*512 + i*32 + lk*8);
    }
  }

  __shared__ float z_lds[4][16][32];
  __shared__ int mask_s[16*130];
  for (int i = tid; i < 16*130; i += 512) mask_s[i] = maskg[i];

  bf16x8 st[16];
  if constexpr (MODE == 2){
    #pragma unroll
    for (int i = 0; i < 16; ++i) st[i] = kreg[(layer == 0) ? (i & 7) : i];
  }

  float c_reg = 0.f, h_reg = 0.f;
  const int gu = tid & 31, gb = tid >> 5;
  const float bzi = bias[u0+gu], bzf = bias[512 + u0+gu];
  const float bzc = bias[1024 + u0+gu], bzo = bias[1536 + u0+gu];
  __syncthreads();

  for (int t = 0; t < nsteps; ++t){
    const int tm = t & 127;
    if constexpr (SYNC){
      if (w == 0){
        const int* fp = nullptr; int tgt = 0;
        if (l < 16){ fp = fown + l*16; tgt = t; }
        else if (l < 32 && layer == 1){ fp = fprod + (l-16)*16; tgt = t + 1; }
        if (fp){
          while (ld_flag(fp) < tgt) __builtin_amdgcn_s_sleep(1);
        }
      }
    }
    __syncthreads();

    if constexpr (MODE == 1){
      f32x4 acc = {0.f, 0.f, 0.f, 0.f};
      if (layer == 0){
        const int pos = dir ? (129 - tm) : tm;
        const unsigned short* xa = x + ((size_t)lr*130 + pos)*256 + lk*8;
        if (t > 0){                                   // issue h-loads FIRST
          const int pm = (tm - 1) & 127;
          const unsigned short* ha = h0 + ((size_t)pm*16 + lr)*512 + lk*8;
          LD16(st, ha);
        }
        #pragma unroll
        for (int i = 0; i < 8; ++i){                  // x-MFMAs overlap h-load latency
          bf16x8 a = *(const bf16x8*)(xa + i*32);
          acc = __builtin_amdgcn_mfma_f32_16x16x32_bf16(a, kreg[i], acc, 0, 0, 0);
        }
        if (t > 0){
          WAIT_VM0();
          #pragma unroll
          for (int i = 0; i < 16; ++i)
            acc = __builtin_amdgcn_mfma_f32_16x16x32_bf16(st[i], wreg[i], acc, 0, 0, 0);
        }
      } else {
        const unsigned short* xa = h0 + ((size_t)tm*16 + lr)*512 + lk*8;
        LD16(st, xa);
        WAIT_VM0();
        #pragma unroll
        for (int i = 0; i < 16; ++i)
          acc = __builtin_amdgcn_mfma_f32_16x16x32_bf16(st[i], kreg[i], acc, 0, 0, 0);
        if (t > 0){
          const int prow = (dir ? (128 - tm) : (tm - 1)) & 127;
          const unsigned short* ha = aproj + ((size_t)lr*128 + prow)*1024 + dir*512 + lk*8;
          LD16(st, ha);
          WAIT_VM0();
          #pragma unroll
          for (int i = 0; i < 16; ++i)
            acc = __builtin_amdgcn_mfma_f32_16x16x32_bf16(st[i], wreg[i], acc, 0, 0, 0);
        }
      }
      #pragma unroll
      for (int r = 0; r < 4; ++r) z_lds[gate][lk*4 + r][half*16 + lr] = acc[r];
    } else if constexpr (MODE == 2){
      #pragma unroll
      for (int i = 0; i < 16; ++i) asm volatile("" : "+v"(st[i]));   // opaque per-iter
      f32x4 acc = {0.f, 0.f, 0.f, 0.f};
      if (layer == 0){
        #pragma unroll
        for (int i = 0; i < 8; ++i)
          acc = __builtin_amdgcn_mfma_f32_16x16x32_bf16(st[i], kreg[i], acc, 0, 0, 0);
        #pragma unroll
        for (int i = 0; i < 16; ++i)
          acc = __builtin_amdgcn_mfma_f32_16x16x32_bf16(st[i], wreg[i], acc, 0, 0, 0);
      } else {
        #pragma unroll
        for (int i = 0; i < 16; ++i)
          acc = __builtin_amdgcn_mfma_f32_16x16x32_bf16(st[i], kreg[i], acc, 0, 0, 0);
        #pragma unroll
        for (int i = 0; i < 16; ++i)
          acc = __builtin_amdgcn_mfma_f32_16x16x32_bf16(st[i], wreg[i], acc, 0, 0, 0);
      }
      #pragma unroll
      for (int r = 0; r < 4; ++r) z_lds[gate][lk*4 + r][half*16 + lr] = acc[r];
    } else {  // MODE 3: loads only
      if (layer == 0){
        const int pos = dir ? (129 - tm) : tm;
        const unsigned short* xa = x + ((size_t)lr*130 + pos)*256 + lk*8;
        bf16x8 xv[8];
        #pragma unroll
        for (int i = 0; i < 8; ++i) xv[i] = *(const bf16x8*)(xa + i*32);
        KEEP8(xv);
        if (t > 0){
          const int pm = (tm - 1) & 127;
          const unsigned short* ha = h0 + ((size_t)pm*16 + lr)*512 + lk*8;
          LD16(st, ha);
          WAIT_VM0();
          KEEP16(st);
        }
      } else {
        const unsigned short* xa = h0 + ((size_t)tm*16 + lr)*512 + lk*8;
        LD16(st, xa);
        WAIT_VM0();
        KEEP16(st);
        if (t > 0){
          const int prow = (dir ? (128 - tm) : (tm - 1)) & 127;
          const unsigned short* ha = aproj + ((size_t)lr*128 + prow)*1024 + dir*512 + lk*8;
          LD16(st, ha);
          WAIT_VM0();
          KEEP16(st);
        }
      }
    }
    __syncthreads();
    {
      unsigned short hb;
      if constexpr (MODE != 3){
        const float zi = z_lds[0][gb][gu] + bzi;
        const float zf = z_lds[1][gb][gu] + bzf;
        const float zc = z_lds[2][gb][gu] + bzc;
        const float zo = z_lds[3][gb][gu] + bzo;
        const float iv = 1.f / (1.f + expf(-zi));
        const float fv = 1.f / (1.f + expf(-zf));
        const float ov = 1.f / (1.f + expf(-zo));
        const float gv = tanhf(zc);
        float cn = fv*c_reg + iv*gv;
        float hn = ov*tanhf(cn);
        const int pos = dir ? (129 - tm) : tm;
        if (mask_s[gb*130 + pos] == 0){ cn = c_reg; hn = h_reg; }
        c_reg = cn; h_reg = hn;
        hb = f2bf(hn);
      } else {
        hb = (unsigned short)t;
      }
      if (layer == 0){
        unsigned short* p = h0 + ((size_t)tm*16 + gb)*512 + u0 + gu;
        BYPASS_ST_SHORT(p, (unsigned)hb);
      } else {
        const int row = dir ? (127 - tm) : tm;
        unsigned short* p = aproj + ((size_t)gb*128 + row)*1024 + dir*512 + u0 + gu;
        BYPASS_ST_SHORT(p, (unsigned)hb);
      }
    }
    asm volatile("s_waitcnt vmcnt(0)" ::: "memory");
    __syncthreads();
    if constexpr (SYNC){
      if (tid == 0){
        int v = t + 1;
        asm volatile("global_store_dword %0, %1, off sc0 sc1" :: "v"(fself), "v"(v) : "memory");
      }
    }
  }
}

// ---------------- bf16 MFMA GEMM (verbatim, proven) ----------------
__global__ __launch_bounds__(256) void gemm_bf16(
    const unsigned short* __restrict__ A, const unsigned short* __restrict__ Bt,
    const float* __restrict__ bias, float* __restrict__ C,
    int M, int N, int K)
{
  __shared__ unsigned short lA[128*32], lB[128*32];
  const int tid = threadIdx.x;
  const int w = tid >> 6, l = tid & 63;
  const int wr = w >> 1, wc = w & 1;
  const int lr = l & 15, lk = l >> 4;
  const int brow = blockIdx.y * 128, bcol = blockIdx.x * 128;
  f32x4 acc[4][4] = {};
  for (int k0 = 0; k0 < K; k0 += 32){
    __syncthreads();
    #pragma unroll
    for (int j = 0; j < 2; ++j){
      const int base = w*2048 + j*1024;
      const int L = base + l*16;
      const int Lg = L ^ (((L >> 7) & 3) << 4);
      const int row = Lg >> 6, kb = Lg & 63;
      gload_lds16((const char*)(A + (size_t)(brow+row)*K + k0) + kb, (char*)lA + base);
      gload_lds16((const char*)(Bt + (size_t)(bcol+row)*K + k0) + kb, (char*)lB + base);
    }
    __syncthreads();
    bf16x8 af[4], bfr[4];
    #pragma unroll
    for (int m = 0; m < 4; ++m){
      const int L = (wr*64 + m*16 + lr)*64 + lk*16;
      const int sp = L ^ (((L >> 7) & 3) << 4);
      af[m] = *(const bf16x8*)((char*)lA + sp);
    }
    #pragma unroll
    for (int n = 0; n < 4; ++n){
      const int L = (wc*64 + n*16 + lr)*64 + lk*16;
      const int sp = L ^ (((L >> 7) & 3) << 4);
      bfr[n] = *(const bf16x8*)((char*)lB + sp);
    }
    #pragma unroll
    for (int m = 0; m < 4; ++m)
      #pragma unroll
      for (int n = 0; n < 4; ++n)
        acc[m][n] = __builtin_amdgcn_mfma_f32_16x16x32_bf16(af[m], bfr[n], acc[m][n], 0, 0, 0);
  }
  #pragma unroll
  for (int m = 0; m < 4; ++m){
    #pragma unroll
    for (int n = 0; n < 4; ++n){
      const int col = bcol + wc*64 + n*16 + lr;
      const float bv = bias[col];
      const int row0 = brow + wr*64 + m*16 + lk*4;
      #pragma unroll
      for (int r = 0; r < 4; ++r)
        C[(size_t)(row0 + r)*N + col] = acc[m][n][r] + bv;
    }
  }
}

extern "C" void kernel_launch(void* const* d_in, const int* in_sizes, int n_in,
                              void* d_out, int out_size, void* d_ws, size_t ws_size,
                              hipStream_t stream){
  (void)in_sizes; (void)n_in; (void)out_size; (void)ws_size;
  const int*   seqs = (const int*)d_in[0];
  const float* emb  = (const float*)d_in[1];
  const float* fk0  = (const float*)d_in[2];
  const float* fr0  = (const float*)d_in[3];
  const float* fb0  = (const float*)d_in[4];
  const float* fk1  = (const float*)d_in[5];
  const float* fr1  = (const float*)d_in[6];
  const float* fb1  = (const float*)d_in[7];
  const float* bk0  = (const float*)d_in[8];
  const float* br0  = (const float*)d_in[9];
  const float* bb0  = (const float*)d_in[10];
  const float* bk1  = (const float*)d_in[11];
  const float* br1  = (const float*)d_in[12];
  const float* bb1  = (const float*)d_in[13];
  const float* Wp   = (const float*)d_in[14];
  const float* bp   = (const float*)d_in[15];
  float* out = (float*)d_out;

  char* ws = (char*)d_ws;
  size_t off = 0;
  auto alloc = [&](size_t b){ size_t o = off; off += (b + 255) & ~(size_t)255; return o; };
  int* flags            = (int*)(ws + alloc(8192));
  unsigned short* x     = (unsigned short*)(ws + alloc((size_t)16*130*256*2));
  int* mask             = (int*)(ws + alloc((size_t)16*130*4));
  unsigned short* fk0T  = (unsigned short*)(ws + alloc((size_t)2048*256*2));
  unsigned short* fr0T  = (unsigned short*)(ws + alloc((size_t)2048*512*2));
  unsigned short* fk1T  = (unsigned short*)(ws + alloc((size_t)2048*512*2));
  unsigned short* fr1T  = (unsigned short*)(ws + alloc((size_t)2048*512*2));
  unsigned short* bk0T  = (unsigned short*)(ws + alloc((size_t)2048*256*2));
  unsigned short* br0T  = (unsigned short*)(ws + alloc((size_t)2048*512*2));
  unsigned short* bk1T  = (unsigned short*)(ws + alloc((size_t)2048*512*2));
  unsigned short* br1T  = (unsigned short*)(ws + alloc((size_t)2048*512*2));
  unsigned short* h0f   = (unsigned short*)(ws + alloc((size_t)128*16*512*2));
  unsigned short* h0b   = (unsigned short*)(ws + alloc((size_t)128*16*512*2));
  unsigned short* aproj = (unsigned short*)(ws + alloc((size_t)2048*1024*2));
  unsigned short* WpT   = (unsigned short*)(ws + alloc((size_t)32000*1024*2));

  int* dflags            = flags + 1024;
  unsigned short* dh0f   = WpT;
  unsigned short* dh0b   = WpT + (size_t)4*1024*1024;
  unsigned short* daproj = WpT + (size_t)8*1024*1024;

  embed_kernel<<<dim3(130,16), 64, 0, stream>>>(seqs, emb, x, mask, flags);

  dim3 tb(32, 8);
  transpose_bf16<<<dim3(64, 8),   tb, 0, stream>>>(fk0, fk0T, 256, 2048);
  transpose_bf16<<<dim3(64, 16),  tb, 0, stream>>>(fr0, fr0T, 512, 2048);
  transpose_bf16<<<dim3(64, 16),  tb, 0, stream>>>(fk1, fk1T, 512, 2048);
  transpose_bf16<<<dim3(64, 16),  tb, 0, stream>>>(fr1, fr1T, 512, 2048);
  transpose_bf16<<<dim3(64, 8),   tb, 0, stream>>>(bk0, bk0T, 256, 2048);
  transpose_bf16<<<dim3(64, 16),  tb, 0, stream>>>(br0, br0T, 512, 2048);
  transpose_bf16<<<dim3(64, 16),  tb, 0, stream>>>(bk1, bk1T, 512, 2048);
  transpose_bf16<<<dim3(64, 16),  tb, 0, stream>>>(br1, br1T, 512, 2048);
  transpose_bf16<<<dim3(1000, 32), tb, 0, stream>>>(Wp, WpT, 1024, 32000);

  lstm_kern<1,1><<<64, 512, 0, stream>>>(x, mask,
      fk0T, fr0T, fk1T, fr1T, bk0T, br0T, bk1T, br1T,
      fb0, fb1, bb0, bb1, h0f, h0b, aproj, flags, 128);

  gemm_bf16<<<dim3(250, 16), 256, 0, stream>>>(aproj, WpT, bp, out, 2048, 32000, 1024);

  // ---- ablation probes (diag buffers only; LDS-tagged) ----
  lstm_kern<0,1><<<64, 512, 0, stream>>>(x, mask,
      fk0T, fr0T, fk1T, fr1T, bk0T, br0T, bk1T, br1T,
      fb0, fb1, bb0, bb1, dh0f, dh0b, daproj, dflags, 1024);
  lstm_kern<0,2><<<64, 512, 0, stream>>>(x, mask,
      fk0T, fr0T, fk1T, fr1T, bk0T, br0T, bk1T, br1T,
      fb0, fb1, bb0, bb1, dh0f, dh0b, daproj, dflags, 2048);
  lstm_kern<0,3><<<64, 512, 0, stream>>>(x, mask,
      fk0T, fr0T, fk1T, fr1T, bk0T, br0T, bk1T, br1T,
      fb0, fb1, bb0, bb1, dh0f, dh0b, daproj, dflags, 2048);
}

// Round 10
// 858.372 us; speedup vs baseline: 33.5307x; 33.5307x over previous
//
#include <hip/hip_runtime.h>

typedef __attribute__((ext_vector_type(8))) short bf16x8;
typedef __attribute__((ext_vector_type(4))) float f32x4;

__device__ __forceinline__ unsigned short f2bf(float x){
  union { float f; unsigned u; } v; v.f = x;
  unsigned r = v.u + 0x7FFFu + ((v.u >> 16) & 1u);
  return (unsigned short)(r >> 16);
}

#define BYPASS_ST_SHORT(base, val) \
  asm volatile("global_store_short %0, %1, off sc0 sc1" :: "v"(base), "v"(val))

__device__ __forceinline__ int ld_flag(const int* p){
  int v;
  asm volatile("global_load_dword %0, %1, off sc0 sc1\n\t"
               "s_waitcnt vmcnt(0)"
               : "=v"(v) : "v"(p) : "memory");
  return v;
}

__device__ __forceinline__ void gload_lds16(const void* g, void* l){
  __builtin_amdgcn_global_load_lds(
      (const __attribute__((address_space(1))) unsigned*)g,
      (__attribute__((address_space(3))) unsigned*)l, 16, 0, 0);
}

// ---------------- embed + mask + flag reset ----------------
__global__ void embed_kernel(const int* __restrict__ seqs, const float* __restrict__ emb,
                             unsigned short* __restrict__ x, int* __restrict__ mask,
                             int* __restrict__ flags){
  const int t = blockIdx.x, b = blockIdx.y, l = threadIdx.x;
  if (t == 0 && b == 0){
    #pragma unroll
    for (int j = 0; j < 16; ++j) flags[l + j*64] = 0;   // 64 slots x 64B
  }
  const int tok = seqs[b*130 + t];
  if (l == 0) mask[b*130 + t] = (tok != 0) ? 1 : 0;
  const float* src = emb + (size_t)tok * 256;
  unsigned short* dst = x + ((size_t)b*130 + t)*256;
  #pragma unroll
  for (int j = 0; j < 4; ++j) dst[l + j*64] = f2bf(src[l + j*64]);
}

// ---------------- fp32 [R,C] -> bf16 [C,R] transpose ----------------
__global__ void transpose_bf16(const float* __restrict__ in, unsigned short* __restrict__ out,
                               int R, int C){
  __shared__ float tile[32][33];
  const int c0 = blockIdx.x*32, r0 = blockIdx.y*32;
  const int tx = threadIdx.x, ty = threadIdx.y;
  #pragma unroll
  for (int j = 0; j < 32; j += 8) tile[ty+j][tx] = in[(size_t)(r0+ty+j)*C + (c0+tx)];
  __syncthreads();
  #pragma unroll
  for (int j = 0; j < 32; j += 8) out[(size_t)(c0+ty+j)*R + (r0+tx)] = f2bf(tile[tx][ty+j]);
}

// ---------------- persistent pipelined 2-layer LSTM (both dirs) ----------------
// R7 structure; ONE change: h staged into LDS once per WG via global_load_lds
// (wave w stages rows 2w,2w+1; source chunk pre-swizzled l^(r&7), linear LDS dest,
// frag reads apply the same XOR). Cuts per-step VMEM requests 8x.
__global__ __launch_bounds__(512, 2) void lstm_coop(
    const unsigned short* __restrict__ x, const int* __restrict__ maskg,
    const unsigned short* __restrict__ fk0T, const unsigned short* __restrict__ fr0T,
    const unsigned short* __restrict__ fk1T, const unsigned short* __restrict__ fr1T,
    const unsigned short* __restrict__ bk0T, const unsigned short* __restrict__ br0T,
    const unsigned short* __restrict__ bk1T, const unsigned short* __restrict__ br1T,
    const float* __restrict__ fb0, const float* __restrict__ fb1,
    const float* __restrict__ bb0, const float* __restrict__ bb1,
    unsigned short* h0f, unsigned short* h0b,
    unsigned short* aproj, int* flags)
{
  const int wg = blockIdx.x;
  const int dir = wg >> 5;
  const int layer = (wg >> 4) & 1;
  const int u0 = (wg & 15) * 32;
  const int tid = threadIdx.x;
  const int w = tid >> 6, l = tid & 63;
  const int gate = w >> 1, half = w & 1;
  const int lr = l & 15, lk = l >> 4;
  const int cglob = gate*512 + u0 + half*16 + lr;

  const unsigned short* kT = (layer == 0) ? (dir ? bk0T : fk0T) : (dir ? bk1T : fk1T);
  const unsigned short* rT = (layer == 0) ? (dir ? br0T : fr0T) : (dir ? br1T : fr1T);
  const float* bias = (layer == 0) ? (dir ? bb0 : fb0) : (dir ? bb1 : fb1);
  unsigned short* h0 = dir ? h0b : h0f;

  int* fown  = flags + (layer*2 + dir)*256;
  int* fprod = flags + dir*256;
  int* fself = fown + (wg & 15)*16;

  bf16x8 wreg[16], kreg[16];
  #pragma unroll
  for (int i = 0; i < 16; ++i)
    wreg[i] = *(const bf16x8*)(rT + (size_t)cglob*512 + i*32 + lk*8);
  if (layer == 0){
    #pragma unroll
    for (int i = 0; i < 8; ++i)
      kreg[i] = *(const bf16x8*)(kT + (size_t)cglob*256 + i*32 + lk*8);
  } else {
    #pragma unroll
    for (int i = 0; i < 16; ++i)
      kreg[i] = *(const bf16x8*)(kT + (size_t)cglob*512 + i*32 + lk*8);
  }

  __shared__ float z_lds[4][16][32];
  __shared__ int mask_s[16*130];
  __shared__ __attribute__((aligned(16))) char h_lds[16*1024];   // 16 rows x 1KB
  __shared__ __attribute__((aligned(16))) char h2_lds[16*1024];
  for (int i = tid; i < 16*130; i += 512) mask_s[i] = maskg[i];

  float c_reg = 0.f, h_reg = 0.f;
  const int gu = tid & 31, gb = tid >> 5;
  const float bzi = bias[u0+gu], bzf = bias[512 + u0+gu];
  const float bzc = bias[1024 + u0+gu], bzo = bias[1536 + u0+gu];
  __syncthreads();

  for (int t = 0; t < 128; ++t){
    // ---- acquire: wave 0 polls peer/producer flags (verbatim R7) ----
    if (w == 0){
      const int* fp = nullptr; int tgt = 0;
      if (l < 16){ fp = fown + l*16; tgt = t; }
      else if (l < 32 && layer == 1){ fp = fprod + (l-16)*16; tgt = t + 1; }
      if (fp){
        while (ld_flag(fp) < tgt) __builtin_amdgcn_s_sleep(1);
      }
    }
    __syncthreads();                                   // S1

    // ---- stage h into LDS once per WG (wave w: rows 2w, 2w+1) ----
    const int r0s = w*2;
    if (layer == 0){
      if (t > 0){
        #pragma unroll
        for (int j = 0; j < 2; ++j){
          const int r = r0s + j;
          const unsigned short* g = h0 + ((size_t)(t-1)*16 + r)*512 + ((l ^ (r & 7))*8);
          gload_lds16(g, h_lds + r*1024);
        }
      }
    } else {
      #pragma unroll
      for (int j = 0; j < 2; ++j){
        const int r = r0s + j;
        const unsigned short* g = h0 + ((size_t)t*16 + r)*512 + ((l ^ (r & 7))*8);
        gload_lds16(g, h_lds + r*1024);
      }
      if (t > 0){
        const int prow = dir ? (128 - t) : (t - 1);
        #pragma unroll
        for (int j = 0; j < 2; ++j){
          const int r = r0s + j;
          const unsigned short* g = aproj + ((size_t)(r*128 + prow))*1024 + dir*512 + ((l ^ (r & 7))*8);
          gload_lds16(g, h2_lds + r*1024);
        }
      }
    }

    // ---- compute z ----
    f32x4 acc = {0.f, 0.f, 0.f, 0.f};
    const int fsw = (lr & 7) << 4;
    if (layer == 0){
      const int pos = dir ? (129 - t) : t;
      const unsigned short* xa = x + ((size_t)lr*130 + pos)*256 + lk*8;
      #pragma unroll
      for (int i = 0; i < 8; ++i){                     // overlaps stage latency
        bf16x8 a = *(const bf16x8*)(xa + i*32);
        acc = __builtin_amdgcn_mfma_f32_16x16x32_bf16(a, kreg[i], acc, 0, 0, 0);
      }
      if (t > 0){
        asm volatile("s_waitcnt vmcnt(0)" ::: "memory");
        __syncthreads();                               // S2
        #pragma unroll
        for (int i = 0; i < 16; ++i){
          bf16x8 a = *(const bf16x8*)(h_lds + lr*1024 + ((lk*16 + i*64) ^ fsw));
          acc = __builtin_amdgcn_mfma_f32_16x16x32_bf16(a, wreg[i], acc, 0, 0, 0);
        }
      }
    } else {
      asm volatile("s_waitcnt vmcnt(0)" ::: "memory");
      __syncthreads();                                 // S2
      #pragma unroll
      for (int i = 0; i < 16; ++i){
        bf16x8 a = *(const bf16x8*)(h_lds + lr*1024 + ((lk*16 + i*64) ^ fsw));
        acc = __builtin_amdgcn_mfma_f32_16x16x32_bf16(a, kreg[i], acc, 0, 0, 0);
      }
      if (t > 0){
        #pragma unroll
        for (int i = 0; i < 16; ++i){
          bf16x8 a = *(const bf16x8*)(h2_lds + lr*1024 + ((lk*16 + i*64) ^ fsw));
          acc = __builtin_amdgcn_mfma_f32_16x16x32_bf16(a, wreg[i], acc, 0, 0, 0);
        }
      }
    }
    // C-frag: col = lane&15, row = (lane>>4)*4 + r  (verified m89/m91)
    #pragma unroll
    for (int r = 0; r < 4; ++r) z_lds[gate][lk*4 + r][half*16 + lr] = acc[r];
    __syncthreads();                                   // S3

    // ---- activation + release (verbatim R7) ----
    {
      const float zi = z_lds[0][gb][gu] + bzi;
      const float zf = z_lds[1][gb][gu] + bzf;
      const float zc = z_lds[2][gb][gu] + bzc;
      const float zo = z_lds[3][gb][gu] + bzo;
      const float iv = 1.f / (1.f + expf(-zi));
      const float fv = 1.f / (1.f + expf(-zf));
      const float ov = 1.f / (1.f + expf(-zo));
      const float gv = tanhf(zc);
      float cn = fv*c_reg + iv*gv;
      float hn = ov*tanhf(cn);
      const int pos = dir ? (129 - t) : t;
      if (mask_s[gb*130 + pos] == 0){ cn = c_reg; hn = h_reg; }
      c_reg = cn; h_reg = hn;
      const unsigned short hb = f2bf(hn);
      if (layer == 0){
        unsigned short* p = h0 + ((size_t)t*16 + gb)*512 + u0 + gu;
        BYPASS_ST_SHORT(p, (unsigned)hb);
      } else {
        const int row = dir ? (127 - t) : t;
        unsigned short* p = aproj + ((size_t)gb*128 + row)*1024 + dir*512 + u0 + gu;
        BYPASS_ST_SHORT(p, (unsigned)hb);
      }
    }
    asm volatile("s_waitcnt vmcnt(0)" ::: "memory");
    __syncthreads();                                   // S4
    if (tid == 0){
      int v = t + 1;
      asm volatile("global_store_dword %0, %1, off sc0 sc1" :: "v"(fself), "v"(v) : "memory");
    }
  }
}

// ---------------- bf16 MFMA GEMM (verbatim, proven) ----------------
__global__ __launch_bounds__(256) void gemm_bf16(
    const unsigned short* __restrict__ A, const unsigned short* __restrict__ Bt,
    const float* __restrict__ bias, float* __restrict__ C,
    int M, int N, int K)
{
  __shared__ unsigned short lA[128*32], lB[128*32];
  const int tid = threadIdx.x;
  const int w = tid >> 6, l = tid & 63;
  const int wr = w >> 1, wc = w & 1;
  const int lr = l & 15, lk = l >> 4;
  const int brow = blockIdx.y * 128, bcol = blockIdx.x * 128;
  f32x4 acc[4][4] = {};
  for (int k0 = 0; k0 < K; k0 += 32){
    __syncthreads();
    #pragma unroll
    for (int j = 0; j < 2; ++j){
      const int base = w*2048 + j*1024;
      const int L = base + l*16;
      const int Lg = L ^ (((L >> 7) & 3) << 4);
      const int row = Lg >> 6, kb = Lg & 63;
      gload_lds16((const char*)(A + (size_t)(brow+row)*K + k0) + kb, (char*)lA + base);
      gload_lds16((const char*)(Bt + (size_t)(bcol+row)*K + k0) + kb, (char*)lB + base);
    }
    __syncthreads();
    bf16x8 af[4], bfr[4];
    #pragma unroll
    for (int m = 0; m < 4; ++m){
      const int L = (wr*64 + m*16 + lr)*64 + lk*16;
      const int sp = L ^ (((L >> 7) & 3) << 4);
      af[m] = *(const bf16x8*)((char*)lA + sp);
    }
    #pragma unroll
    for (int n = 0; n < 4; ++n){
      const int L = (wc*64 + n*16 + lr)*64 + lk*16;
      const int sp = L ^ (((L >> 7) & 3) << 4);
      bfr[n] = *(const bf16x8*)((char*)lB + sp);
    }
    #pragma unroll
    for (int m = 0; m < 4; ++m)
      #pragma unroll
      for (int n = 0; n < 4; ++n)
        acc[m][n] = __builtin_amdgcn_mfma_f32_16x16x32_bf16(af[m], bfr[n], acc[m][n], 0, 0, 0);
  }
  #pragma unroll
  for (int m = 0; m < 4; ++m){
    #pragma unroll
    for (int n = 0; n < 4; ++n){
      const int col = bcol + wc*64 + n*16 + lr;
      const float bv = bias[col];
      const int row0 = brow + wr*64 + m*16 + lk*4;
      #pragma unroll
      for (int r = 0; r < 4; ++r)
        C[(size_t)(row0 + r)*N + col] = acc[m][n][r] + bv;
    }
  }
}

extern "C" void kernel_launch(void* const* d_in, const int* in_sizes, int n_in,
                              void* d_out, int out_size, void* d_ws, size_t ws_size,
                              hipStream_t stream){
  (void)in_sizes; (void)n_in; (void)out_size; (void)ws_size;
  const int*   seqs = (const int*)d_in[0];
  const float* emb  = (const float*)d_in[1];
  const float* fk0  = (const float*)d_in[2];
  const float* fr0  = (const float*)d_in[3];
  const float* fb0  = (const float*)d_in[4];
  const float* fk1  = (const float*)d_in[5];
  const float* fr1  = (const float*)d_in[6];
  const float* fb1  = (const float*)d_in[7];
  const float* bk0  = (const float*)d_in[8];
  const float* br0  = (const float*)d_in[9];
  const float* bb0  = (const float*)d_in[10];
  const float* bk1  = (const float*)d_in[11];
  const float* br1  = (const float*)d_in[12];
  const float* bb1  = (const float*)d_in[13];
  const float* Wp   = (const float*)d_in[14];
  const float* bp   = (const float*)d_in[15];
  float* out = (float*)d_out;

  char* ws = (char*)d_ws;
  size_t off = 0;
  auto alloc = [&](size_t b){ size_t o = off; off += (b + 255) & ~(size_t)255; return o; };
  int* flags            = (int*)(ws + alloc(4096));
  unsigned short* x     = (unsigned short*)(ws + alloc((size_t)16*130*256*2));
  int* mask             = (int*)(ws + alloc((size_t)16*130*4));
  unsigned short* fk0T  = (unsigned short*)(ws + alloc((size_t)2048*256*2));
  unsigned short* fr0T  = (unsigned short*)(ws + alloc((size_t)2048*512*2));
  unsigned short* fk1T  = (unsigned short*)(ws + alloc((size_t)2048*512*2));
  unsigned short* fr1T  = (unsigned short*)(ws + alloc((size_t)2048*512*2));
  unsigned short* bk0T  = (unsigned short*)(ws + alloc((size_t)2048*256*2));
  unsigned short* br0T  = (unsigned short*)(ws + alloc((size_t)2048*512*2));
  unsigned short* bk1T  = (unsigned short*)(ws + alloc((size_t)2048*512*2));
  unsigned short* br1T  = (unsigned short*)(ws + alloc((size_t)2048*512*2));
  unsigned short* h0f   = (unsigned short*)(ws + alloc((size_t)128*16*512*2));
  unsigned short* h0b   = (unsigned short*)(ws + alloc((size_t)128*16*512*2));
  unsigned short* aproj = (unsigned short*)(ws + alloc((size_t)2048*1024*2));
  unsigned short* WpT   = (unsigned short*)(ws + alloc((size_t)32000*1024*2));

  embed_kernel<<<dim3(130,16), 64, 0, stream>>>(seqs, emb, x, mask, flags);

  dim3 tb(32, 8);
  transpose_bf16<<<dim3(64, 8),   tb, 0, stream>>>(fk0, fk0T, 256, 2048);
  transpose_bf16<<<dim3(64, 16),  tb, 0, stream>>>(fr0, fr0T, 512, 2048);
  transpose_bf16<<<dim3(64, 16),  tb, 0, stream>>>(fk1, fk1T, 512, 2048);
  transpose_bf16<<<dim3(64, 16),  tb, 0, stream>>>(fr1, fr1T, 512, 2048);
  transpose_bf16<<<dim3(64, 8),   tb, 0, stream>>>(bk0, bk0T, 256, 2048);
  transpose_bf16<<<dim3(64, 16),  tb, 0, stream>>>(br0, br0T, 512, 2048);
  transpose_bf16<<<dim3(64, 16),  tb, 0, stream>>>(bk1, bk1T, 512, 2048);
  transpose_bf16<<<dim3(64, 16),  tb, 0, stream>>>(br1, br1T, 512, 2048);
  transpose_bf16<<<dim3(1000, 32), tb, 0, stream>>>(Wp, WpT, 1024, 32000);

  lstm_coop<<<64, 512, 0, stream>>>(x, mask,
      fk0T, fr0T, fk1T, fr1T, bk0T, br0T, bk1T, br1T,
      fb0, fb1, bb0, bb1, h0f, h0b, aproj, flags);

  gemm_bf16<<<dim3(250, 16), 256, 0, stream>>>(aproj, WpT, bp, out, 2048, 32000, 1024);
}